// Round 11
// baseline (52.611 us; speedup 1.0000x reference)
//
#include <hip/hip_runtime.h>
#include <hip/hip_bf16.h>
#include <math.h>

// CoSent clustering loss on MI355X — round 11.
// 3-kernel pipeline: segment sums are linear, so per-row storage (wsAB) and
// the reduce_rows kernel are unnecessary — the GEMM epilogue bins by LABEL
// (LDS bins) and atomically accumulates into 128 label-slot accumulators.
// Main GEMM: r10 structure (fp8 superfrag-major, reg double-buffer, counted
// vmcnt(8)) + closed-form triangular decode + v_exp_f32 with folded log2e.

typedef __attribute__((ext_vector_type(2))) long l2;     // two fp8 frags
typedef __attribute__((ext_vector_type(4))) float f32x4;

#define N_EMB 8192
#define D_EMB 256
#define NUM_LABELS 128
#define PAN 128
#define NPAN (N_EMB / PAN)           // 64
#define NTRI (NPAN * (NPAN + 1) / 2) // 2080 = 8 * 260
#define NSLOT 128

// ---- DPP 16-lane reduction helpers ----
template <int CTRL>
__device__ __forceinline__ float dpp_add(float x) {
    int y = __builtin_amdgcn_update_dpp(0, __builtin_bit_cast(int, x),
                                        CTRL, 0xF, 0xF, false);
    return x + __builtin_bit_cast(float, y);
}
__device__ __forceinline__ float red16(float x) {
    x = dpp_add<0xB1>(x);    // quad_perm xor1
    x = dpp_add<0x4E>(x);    // quad_perm xor2
    x = dpp_add<0x124>(x);   // row_ror:4
    x = dpp_add<0x128>(x);   // row_ror:8
    return x;
}

__device__ __forceinline__ float exp2hw(float x) {
    float r;
    asm("v_exp_f32 %0, %1" : "=v"(r) : "v"(x));
    return r;
}

// ---------------------------------------------------------------- normalize
// Emits fp8 in superfrag-major order (see r10 comment) + zeroes the 128
// label-slot accumulators (blocks 0..127, 256 floats each).
__global__ __launch_bounds__(256) void normalize_kernel(const float* __restrict__ emb,
                                                        char* __restrict__ e8,
                                                        float* __restrict__ slots) {
    const int wid = threadIdx.x >> 6, lane = threadIdx.x & 63;
    const int row = blockIdx.x * 4 + wid;
    const f32x4 x = *(const f32x4*)(emb + (size_t)row * D_EMB + lane * 4);
    float ss = x[0]*x[0] + x[1]*x[1] + x[2]*x[2] + x[3]*x[3];
    #pragma unroll
    for (int off = 32; off >= 1; off >>= 1) ss += __shfl_xor(ss, off);
    const float r = 1.0f / fmaxf(sqrtf(ss), 1e-12f);
    int v = __builtin_amdgcn_cvt_pk_fp8_f32(x[0] * r, x[1] * r, 0, false);
    v = __builtin_amdgcn_cvt_pk_fp8_f32(x[2] * r, x[3] * r, v, true);
    const int u    = lane >> 4;
    const int half = (lane >> 3) & 1;
    const int lp   = ((lane >> 1) & 3) * 16 + (row & 15);
    const int j0   = (lane & 1) * 4;
    char* dst = e8 + ((size_t)(row >> 4) * 4 + u) * 1024 + lp * 16 + half * 8 + j0;
    *(unsigned*)dst = (unsigned)v;
    if (blockIdx.x < NSLOT) slots[blockIdx.x * 256 + threadIdx.x] = 0.f;
}

// ---- pinned coalesced superfrag load: SGPR base + VGPR offset + literal ----
#define LOADF(dst, voff, sb, OFFSTR) \
    asm volatile("global_load_dwordx4 %0, %1, %2 offset:" OFFSTR \
                 : "=v"(dst) : "v"(voff), "s"(sb))

#define ISSUE(PA_, PB_, OFFSTR) \
    LOADF(PA_[0], voA[0], sbA, OFFSTR); LOADF(PA_[1], voA[1], sbA, OFFSTR); \
    LOADF(PA_[2], voA[2], sbA, OFFSTR); LOADF(PA_[3], voA[3], sbA, OFFSTR); \
    LOADF(PB_[0], voB[0], sbB, OFFSTR); LOADF(PB_[1], voB[1], sbB, OFFSTR); \
    LOADF(PB_[2], voB[2], sbB, OFFSTR); LOADF(PB_[3], voB[3], sbB, OFFSTR)

#define WAITV(NSTR) \
    asm volatile("s_waitcnt vmcnt(" NSTR ")" ::: "memory"); \
    __builtin_amdgcn_sched_barrier(0)

#define MF8(a, b, c) __builtin_amdgcn_mfma_f32_16x16x32_fp8_fp8(a, b, c, 0, 0, 0)

#define MROW(PA_, PB_, mi, H) \
    acc[mi][0] = MF8(PA_[mi][H], PB_[0][H], acc[mi][0]); \
    acc[mi][1] = MF8(PA_[mi][H], PB_[1][H], acc[mi][1]); \
    acc[mi][2] = MF8(PA_[mi][H], PB_[2][H], acc[mi][2]); \
    acc[mi][3] = MF8(PA_[mi][H], PB_[3][H], acc[mi][3]);

#define MFMA32(PA_, PB_) \
    __builtin_amdgcn_s_setprio(1); \
    MROW(PA_, PB_, 0, 0) MROW(PA_, PB_, 1, 0) MROW(PA_, PB_, 2, 0) MROW(PA_, PB_, 3, 0) \
    MROW(PA_, PB_, 0, 1) MROW(PA_, PB_, 1, 1) MROW(PA_, PB_, 2, 1) MROW(PA_, PB_, 3, 1) \
    __builtin_amdgcn_s_setprio(0)

// ----------------------------------------------------------------- main GEMM
// Triangular 128x128 tiles, 4 waves (2x2), per-wave 64x64 = 4x4 frags.
__global__ __launch_bounds__(256, 3) void cosent_main(const char* __restrict__ e8,
                                                      const int* __restrict__ labels,
                                                      const float* __restrict__ scale,
                                                      float* __restrict__ slots) {
    __shared__ float rowsc[2][PAN][2];
    __shared__ float colsc[2][PAN][2];
    __shared__ float binA[NUM_LABELS], binB[NUM_LABELS];
    __shared__ int labR[PAN], labC[PAN];

    // XCD-bijective swizzle (2080 = 8*260) + closed-form triangular decode.
    const int bid = blockIdx.x;
    const int swz = (bid & 7) * 260 + (bid >> 3);
    int by = (int)((129.0f - sqrtf(16641.0f - 8.0f * (float)swz)) * 0.5f);
    by = by < 0 ? 0 : (by > 63 ? 63 : by);
    while (by < 63 && (by + 1) * (129 - (by + 1)) / 2 <= swz) ++by;
    while (by > 0 && by * (129 - by) / 2 > swz) --by;
    const int bx = by + (swz - by * (129 - by) / 2);
    const bool diag = (bx == by);
    const int rowBase = by * PAN, colBase = bx * PAN;

    const int tid = threadIdx.x, lane = tid & 63, wid = tid >> 6;
    const int wm = wid >> 1, wn = wid & 1;
    const int rr = lane & 15, kh = lane >> 4;

    if (tid < PAN) { labR[tid] = labels[rowBase + tid]; binA[tid] = 0.f; binB[tid] = 0.f; }
    else           { labC[tid - PAN] = labels[colBase + tid - PAN]; }

    // per-frag-group voffsets (bytes): group (w*4+i) stride 4096, lane 16B
    const int laneB = lane * 16;
    int voA[4], voB[4];
    #pragma unroll
    for (int i = 0; i < 4; ++i) {
        voA[i] = (wm * 4 + i) * 4096 + laneB;
        voB[i] = (wn * 4 + i) * 4096 + laneB;
    }
    const char* sbA = e8 + (size_t)rowBase * 256;   // byte base of row panel
    const char* sbB = e8 + (size_t)colBase * 256;

    f32x4 acc[4][4];
    #pragma unroll
    for (int i = 0; i < 4; ++i)
        #pragma unroll
        for (int j = 0; j < 4; ++j) acc[i][j] = (f32x4){0.f, 0.f, 0.f, 0.f};

    l2 pA[4], pB[4], qA[4], qB[4];

    ISSUE(pA, pB, "0");                                   // u=0
    ISSUE(qA, qB, "1024"); WAITV("8"); MFMA32(pA, pB);    // u=1 | u0
    ISSUE(pA, pB, "2048"); WAITV("8"); MFMA32(qA, qB);    // u=2 | u1
    ISSUE(qA, qB, "3072"); WAITV("8"); MFMA32(pA, pB);    // u=3 | u2
    WAITV("0"); MFMA32(qA, qB);                           //     | u3

    __syncthreads();   // labels + bins visible (moved after K-loop: no LDS dep before)

    // ------------- fused epilogue: one exp per element, row + col partials
    const float s2 = *scale * 1.44269504088896f;   // fold log2(e): e^x = 2^(x*log2e)
    int lc[4];
    #pragma unroll
    for (int ni = 0; ni < 4; ++ni) lc[ni] = labC[wn * 64 + ni * 16 + rr];
    float colA[4] = {0.f, 0.f, 0.f, 0.f}, colB[4] = {0.f, 0.f, 0.f, 0.f};

    #pragma unroll
    for (int mi = 0; mi < 4; ++mi) {
        #pragma unroll
        for (int r = 0; r < 4; ++r) {
            const int rowL = wm * 64 + mi * 16 + kh * 4 + r;
            const int lr = labR[rowL];
            float asum = 0.f, bsum = 0.f;
            #pragma unroll
            for (int ni = 0; ni < 4; ++ni) {
                const int colL = wn * 64 + ni * 16 + rr;
                const float val = acc[mi][ni][r] * s2;
                const bool pos = (lr == lc[ni]);
                float ex = exp2hw(pos ? -val : val);
                if (diag && rowL == colL) ex = 0.f;   // exclude self-pairs
                if (pos) { asum += ex; colA[ni] += ex; }
                else     { bsum += ex; colB[ni] += ex; }
            }
            asum = red16(asum);
            bsum = red16(bsum);
            if (rr == 0) { rowsc[wn][rowL][0] = asum; rowsc[wn][rowL][1] = bsum; }
        }
    }

    if (!diag) {   // col-side (transposed contribution via symmetry)
        #pragma unroll
        for (int ni = 0; ni < 4; ++ni) {
            float a = colA[ni], b = colB[ni];
            a += __shfl_xor(a, 16); a += __shfl_xor(a, 32);
            b += __shfl_xor(b, 16); b += __shfl_xor(b, 32);
            if (lane < 16) {
                colsc[wm][wn * 64 + ni * 16 + lane][0] = a;
                colsc[wm][wn * 64 + ni * 16 + lane][1] = b;
            }
        }
    }
    __syncthreads();

    // ------------- label binning (LDS) then one atomic pair per label
    if (tid < PAN) {
        const float ra = rowsc[0][tid][0] + rowsc[1][tid][0];
        const float rb = rowsc[0][tid][1] + rowsc[1][tid][1];
        atomicAdd(&binA[labR[tid]], ra);
        atomicAdd(&binB[labR[tid]], rb);
        if (!diag) {
            const float ca = colsc[0][tid][0] + colsc[1][tid][0];
            const float cb = colsc[0][tid][1] + colsc[1][tid][1];
            atomicAdd(&binA[labC[tid]], ca);
            atomicAdd(&binB[labC[tid]], cb);
        }
    }
    __syncthreads();

    if (tid < NUM_LABELS) {
        float* slot = slots + (size_t)(bid & (NSLOT - 1)) * (NUM_LABELS * 2);
        const float a = binA[tid], b = binB[tid];
        if (a != 0.f) atomicAdd(&slot[tid * 2 + 0], a);
        if (b != 0.f) atomicAdd(&slot[tid * 2 + 1], b);
    }
}

// ----------------------------------------------------------------- finalize
__global__ __launch_bounds__(256) void finalize_kernel(const float* __restrict__ slots,
                                                       const int* __restrict__ labels,
                                                       float* __restrict__ out) {
    __shared__ int cnt[NUM_LABELS];
    __shared__ float w2[4];
    const int tid = threadIdx.x;
    if (tid < NUM_LABELS) cnt[tid] = 0;
    __syncthreads();
    for (int i = tid; i < N_EMB; i += 256) atomicAdd(&cnt[labels[i]], 1);
    __syncthreads();

    float A = 0.f, B = 0.f;
    if (tid < NUM_LABELS) {
        #pragma unroll 8
        for (int s = 0; s < NSLOT; ++s) {
            const float* p = slots + (size_t)s * (NUM_LABELS * 2) + tid * 2;
            A += p[0]; B += p[1];
        }
    }
    float v = (tid < NUM_LABELS && cnt[tid] >= 2) ? A * B : 0.f;
    #pragma unroll
    for (int off = 32; off >= 1; off >>= 1) v += __shfl_xor(v, off);
    if ((tid & 63) == 0) w2[tid >> 6] = v;
    __syncthreads();
    if (tid == 0) out[0] = logf(1.0f + w2[0] + w2[1] + w2[2] + w2[3]);
}

// ------------------------------------------------------------------ launcher
extern "C" void kernel_launch(void* const* d_in, const int* in_sizes, int n_in,
                              void* d_out, int out_size, void* d_ws, size_t ws_size,
                              hipStream_t stream) {
    const float* emb    = (const float*)d_in[0];
    const int*   labels = (const int*)d_in[1];
    const float* scale  = (const float*)d_in[2];
    float* out = (float*)d_out;

    char*  e8    = (char*)d_ws;                                   // 2 MB (superfrag fp8)
    float* slots = (float*)((char*)d_ws + (size_t)N_EMB * D_EMB); // 128 KB

    normalize_kernel<<<N_EMB / 4, 256, 0, stream>>>(emb, e8, slots);
    cosent_main<<<NTRI, 256, 0, stream>>>(e8, labels, scale, slots);
    finalize_kernel<<<1, 256, 0, stream>>>(slots, labels, out);
}